// Round 2
// baseline (425.173 us; speedup 1.0000x reference)
//
#include <hip/hip_runtime.h>
#include <math.h>

#define N_ROWS 200000
#define D 200
#define OUT1 300
#define OUT2 400
#define S1_BLOCKS 512
#define SLAB 20                    // rows per block per iteration (4 groups x 5 rows)
#define STRIDE (S1_BLOCKS * SLAB)  // 10240 rows; 200000 % 20 == 0 -> no tail

// ---------------------------------------------------------------------------
// Stage 1: column-sum of a [N_ROWS, D] f32 matrix (both branches via grid.y).
// 4-deep unrolled: 4 independent float4 loads in flight per thread.
// partial layout: [2 branches][D cols][S1_BLOCKS] floats (fully written).
// ---------------------------------------------------------------------------
__global__ __launch_bounds__(256)
void colsum_kernel(const float* __restrict__ userH,
                   const float* __restrict__ postH,
                   float* __restrict__ partial)
{
    const int br = blockIdx.y;
    const float* __restrict__ H = (br == 0) ? userH : postH;
    const int t  = threadIdx.x;
    const int q  = t % 50;   // float4 index within the row
    const int sr = t / 50;   // sub-row 0..4 (sr==5 -> idle lanes 250..255)

    float4 a0 = make_float4(0.f, 0.f, 0.f, 0.f);
    float4 a1 = a0, a2 = a0, a3 = a0;

    if (sr < 5) {
        // rows row, row+5, row+10, row+15: 4 independent loads per iteration.
        // Since N_ROWS % SLAB == 0, row+15 < N_ROWS holds for every generated
        // slab -> no bounds checks, no tail loop.
        for (int row = blockIdx.x * SLAB + sr; row + 15 < N_ROWS; row += STRIDE) {
            const float4 v0 = *reinterpret_cast<const float4*>(H + (size_t)(row     ) * D + q * 4);
            const float4 v1 = *reinterpret_cast<const float4*>(H + (size_t)(row +  5) * D + q * 4);
            const float4 v2 = *reinterpret_cast<const float4*>(H + (size_t)(row + 10) * D + q * 4);
            const float4 v3 = *reinterpret_cast<const float4*>(H + (size_t)(row + 15) * D + q * 4);
            a0.x += v0.x; a0.y += v0.y; a0.z += v0.z; a0.w += v0.w;
            a1.x += v1.x; a1.y += v1.y; a1.z += v1.z; a1.w += v1.w;
            a2.x += v2.x; a2.y += v2.y; a2.z += v2.z; a2.w += v2.w;
            a3.x += v3.x; a3.y += v3.y; a3.z += v3.z; a3.w += v3.w;
        }
        a0.x += a1.x; a0.y += a1.y; a0.z += a1.z; a0.w += a1.w;
        a2.x += a3.x; a2.y += a3.y; a2.z += a3.z; a2.w += a3.w;
        a0.x += a2.x; a0.y += a2.y; a0.z += a2.z; a0.w += a2.w;
    }

    __shared__ float part[5][D];   // 4 KB
    if (sr < 5) {
        part[sr][q * 4 + 0] = a0.x;
        part[sr][q * 4 + 1] = a0.y;
        part[sr][q * 4 + 2] = a0.z;
        part[sr][q * 4 + 3] = a0.w;
    }
    __syncthreads();

    if (t < D) {
        float s = 0.f;
        #pragma unroll
        for (int r = 0; r < 5; ++r) s += part[r][t];
        partial[((size_t)br * D + t) * S1_BLOCKS + blockIdx.x] = s;
    }
}

// ---------------------------------------------------------------------------
// Stage 2: finish reduction -> means -> tiny MLP -> softmax -> output scalar.
// Single block, 512 threads.
// ---------------------------------------------------------------------------
__global__ __launch_bounds__(512)
void mlp_kernel(const float* __restrict__ partial,
                const float* __restrict__ W1u, const float* __restrict__ b1u,
                const float* __restrict__ W2u, const float* __restrict__ b2u,
                const float* __restrict__ W1p, const float* __restrict__ b1p,
                const float* __restrict__ W2p, const float* __restrict__ b2p,
                const float* __restrict__ Wout, const float* __restrict__ bout,
                float* __restrict__ out)
{
    __shared__ float m [2][D];     // column means
    __shared__ float g1[2][OUT1];
    __shared__ float g2[2][OUT2];
    __shared__ float sm[2][OUT2];

    const int t = threadIdx.x;

    // --- finish the column-sum: each of 400 threads owns one (branch,col) ---
    if (t < 2 * D) {
        const float4* p =
            reinterpret_cast<const float4*>(partial + (size_t)t * S1_BLOCKS);
        float4 a = make_float4(0.f, 0.f, 0.f, 0.f);
        for (int k = 0; k < S1_BLOCKS / 4; ++k) {
            const float4 v = p[k];
            a.x += v.x; a.y += v.y; a.z += v.z; a.w += v.w;
        }
        m[t / D][t % D] = (a.x + a.y + a.z + a.w) * (1.0f / (float)N_ROWS);
    }
    __syncthreads();

    // --- g1 = relu(m @ W1 + b1): 2*300 jobs, dot length 200 ---
    for (int p = t; p < 2 * OUT1; p += 512) {
        const int br = p / OUT1;
        const int j  = p % OUT1;
        const float* __restrict__ W1 = br ? W1p : W1u;
        const float* __restrict__ b1 = br ? b1p : b1u;
        float s = b1[j];
        for (int c = 0; c < D; ++c) s += m[br][c] * W1[c * OUT1 + j];
        g1[br][j] = fmaxf(s, 0.f);
    }
    __syncthreads();

    // --- g2 = g1 @ W2 + b2: 2*400 jobs, dot length 300 ---
    for (int p = t; p < 2 * OUT2; p += 512) {
        const int br = p / OUT2;
        const int k  = p % OUT2;
        const float* __restrict__ W2 = br ? W2p : W2u;
        const float* __restrict__ b2 = br ? b2p : b2u;
        float s = b2[k];
        for (int j = 0; j < OUT1; ++j) s += g1[br][j] * W2[j * OUT2 + k];
        g2[br][k] = s;
    }
    __syncthreads();

    // --- softmax per branch: wave 0 -> branch 0, wave 1 -> branch 1 ---
    const int wave = t >> 6;
    const int lane = t & 63;
    if (wave < 2) {
        const int br = wave;
        float mx = -INFINITY;
        for (int k = lane; k < OUT2; k += 64) mx = fmaxf(mx, g2[br][k]);
        #pragma unroll
        for (int off = 32; off > 0; off >>= 1) mx = fmaxf(mx, __shfl_xor(mx, off));
        float sum = 0.f;
        for (int k = lane; k < OUT2; k += 64) {
            const float e = expf(g2[br][k] - mx);
            sm[br][k] = e;
            sum += e;
        }
        #pragma unroll
        for (int off = 32; off > 0; off >>= 1) sum += __shfl_xor(sum, off);
        const float inv = 1.0f / sum;
        for (int k = lane; k < OUT2; k += 64) sm[br][k] *= inv;
    }
    __syncthreads();

    // --- out = sigmoid((sm_u + sm_p) @ W_out + b_out) ---
    if (wave == 0) {
        float s = 0.f;
        for (int k = lane; k < OUT2; k += 64)
            s += (sm[0][k] + sm[1][k]) * Wout[k];
        #pragma unroll
        for (int off = 32; off > 0; off >>= 1) s += __shfl_xor(s, off);
        if (lane == 0)
            out[0] = 1.0f / (1.0f + expf(-(s + bout[0])));
    }
}

// ---------------------------------------------------------------------------
extern "C" void kernel_launch(void* const* d_in, const int* in_sizes, int n_in,
                              void* d_out, int out_size, void* d_ws, size_t ws_size,
                              hipStream_t stream) {
    const float* userH = (const float*)d_in[0];
    const float* postH = (const float*)d_in[1];
    const float* W1u   = (const float*)d_in[2];
    const float* b1u   = (const float*)d_in[3];
    const float* W2u   = (const float*)d_in[4];
    const float* b2u   = (const float*)d_in[5];
    const float* W1p   = (const float*)d_in[6];
    const float* b1p   = (const float*)d_in[7];
    const float* W2p   = (const float*)d_in[8];
    const float* b2p   = (const float*)d_in[9];
    const float* Wout  = (const float*)d_in[10];
    const float* bout  = (const float*)d_in[11];

    float* partial = (float*)d_ws;   // 2*200*512*4 = 819,200 bytes

    dim3 grid1(S1_BLOCKS, 2);
    colsum_kernel<<<grid1, 256, 0, stream>>>(userH, postH, partial);

    mlp_kernel<<<1, 512, 0, stream>>>(partial,
                                      W1u, b1u, W2u, b2u,
                                      W1p, b1p, W2p, b2p,
                                      Wout, bout, (float*)d_out);
}

// Round 3
// 390.666 us; speedup vs baseline: 1.0883x; 1.0883x over previous
//
#include <hip/hip_runtime.h>
#include <math.h>

#define N_ROWS 200000
#define D 200
#define OUT1 300
#define OUT2 400
#define S1B 1024          // stage-1 blocks per branch (2048 total -> 8 blocks/CU)

// ---------------------------------------------------------------------------
// Stage 1: column-sum of [N_ROWS, D] f32 (branch = blockIdx.y).
// Simple 1-load loop (round-1 structure, which beat the manual unroll).
// partial layout: [2][S1B][D] floats -- coalesced 800 B store per block.
// ---------------------------------------------------------------------------
__global__ __launch_bounds__(256)
void colsum_kernel(const float* __restrict__ userH,
                   const float* __restrict__ postH,
                   float* __restrict__ partial)
{
    const int br = blockIdx.y;
    const float* __restrict__ H = (br == 0) ? userH : postH;
    const int t  = threadIdx.x;
    const int q  = t % 50;   // float4 index within the row
    const int sr = t / 50;   // sub-row 0..4 (lanes 250..255 idle)

    float4 acc = make_float4(0.f, 0.f, 0.f, 0.f);
    if (sr < 5) {
        for (int row = blockIdx.x * 5 + sr; row < N_ROWS; row += S1B * 5) {
            const float4 v =
                *reinterpret_cast<const float4*>(H + (size_t)row * D + q * 4);
            acc.x += v.x; acc.y += v.y; acc.z += v.z; acc.w += v.w;
        }
    }

    __shared__ float part[5][D];   // 4 KB
    if (sr < 5) {
        part[sr][q * 4 + 0] = acc.x;
        part[sr][q * 4 + 1] = acc.y;
        part[sr][q * 4 + 2] = acc.z;
        part[sr][q * 4 + 3] = acc.w;
    }
    __syncthreads();

    if (t < D) {
        float s = 0.f;
        #pragma unroll
        for (int r = 0; r < 5; ++r) s += part[r][t];
        partial[((size_t)br * S1B + blockIdx.x) * D + t] = s;
    }
}

// ---------------------------------------------------------------------------
// Stage 2: finish reduction -> means -> MLP -> softmax -> sigmoid scalar.
// One block, 1024 threads. Every dot is chunked so loads are parallel and
// float4-vectorized along the OUTPUT dim (coalesced per wave), then a short
// LDS tree-reduce combines chunk partials.
// ---------------------------------------------------------------------------
__global__ __launch_bounds__(1024)
void mlp_kernel(const float* __restrict__ partial,
                const float* __restrict__ W1u, const float* __restrict__ b1u,
                const float* __restrict__ W2u, const float* __restrict__ b2u,
                const float* __restrict__ W1p, const float* __restrict__ b1p,
                const float* __restrict__ W2p, const float* __restrict__ b2p,
                const float* __restrict__ Wout, const float* __restrict__ bout,
                float* __restrict__ out)
{
    __shared__ float4 pm [2][50][8];    // 12.8 KB  col-mean chunk partials
    __shared__ float  m  [2][D];        //  1.6 KB
    __shared__ float4 pg1[2][75][8];    // 19.2 KB  g1 chunk partials
    __shared__ float  g1 [2][OUT1];     //  2.4 KB
    __shared__ float4 pg2[2][100][5];   // 16.0 KB  g2 chunk partials
    __shared__ float  g2s[2][OUT2];     //  3.2 KB
    __shared__ float  sm [2][OUT2];     //  3.2 KB

    const int t = threadIdx.x;

    // --- phase 0: reduce partial[2][1024][200] -> m[2][200] -----------------
    // 800 jobs: (chunk of 128 blocks) x (br) x (col-quad). 1 round.
    if (t < 800) {
        const int chunk = t / 100, r = t % 100, br = r / 50, cq = r % 50;
        const float* base =
            partial + ((size_t)br * S1B + (size_t)chunk * 128) * D + cq * 4;
        float4 a = make_float4(0.f, 0.f, 0.f, 0.f);
        #pragma unroll 8
        for (int i = 0; i < 128; ++i) {
            const float4 v = *reinterpret_cast<const float4*>(base + (size_t)i * D);
            a.x += v.x; a.y += v.y; a.z += v.z; a.w += v.w;
        }
        pm[br][cq][chunk] = a;
    }
    __syncthreads();
    if (t < 2 * D) {
        const int br = t / D, col = t % D, cq = col / 4, comp = col % 4;
        float s = 0.f;
        #pragma unroll
        for (int ch = 0; ch < 8; ++ch)
            s += reinterpret_cast<const float*>(&pm[br][cq][ch])[comp];
        m[br][col] = s * (1.0f / (float)N_ROWS);
    }
    __syncthreads();

    // --- phase 1: g1 = relu(m @ W1 + b1) ------------------------------------
    // 1200 jobs: (c-chunk of 25) x (br) x (j-quad of 75). 2 rounds.
    for (int job = t; job < 1200; job += 1024) {
        const int chunk = job / 150, r = job % 150, br = r / 75, jq = r % 75;
        const float* __restrict__ W1 = br ? W1p : W1u;
        const float* __restrict__ mb = m[br];
        const int c0 = chunk * 25;
        float4 a = make_float4(0.f, 0.f, 0.f, 0.f);
        #pragma unroll 5
        for (int i = 0; i < 25; ++i) {
            const float4 w =
                *reinterpret_cast<const float4*>(W1 + (size_t)(c0 + i) * OUT1 + jq * 4);
            const float mv = mb[c0 + i];
            a.x += mv * w.x; a.y += mv * w.y; a.z += mv * w.z; a.w += mv * w.w;
        }
        pg1[br][jq][chunk] = a;
    }
    __syncthreads();
    if (t < 2 * OUT1) {
        const int br = t / OUT1, j = t % OUT1, jq = j / 4, comp = j % 4;
        float s = (br ? b1p : b1u)[j];
        #pragma unroll
        for (int ch = 0; ch < 8; ++ch)
            s += reinterpret_cast<const float*>(&pg1[br][jq][ch])[comp];
        g1[br][j] = fmaxf(s, 0.f);
    }
    __syncthreads();

    // --- phase 2: g2 = g1 @ W2 + b2 -----------------------------------------
    // 1000 jobs: (j-chunk of 60) x (br) x (k-quad of 100). 1 round.
    if (t < 1000) {
        const int chunk = t / 200, r = t % 200, br = r / 100, kq = r % 100;
        const float* __restrict__ W2 = br ? W2p : W2u;
        const float* __restrict__ gb = g1[br];
        const int j0 = chunk * 60;
        float4 a = make_float4(0.f, 0.f, 0.f, 0.f);
        #pragma unroll 6
        for (int i = 0; i < 60; ++i) {
            const float4 w =
                *reinterpret_cast<const float4*>(W2 + (size_t)(j0 + i) * OUT2 + kq * 4);
            const float gv = gb[j0 + i];
            a.x += gv * w.x; a.y += gv * w.y; a.z += gv * w.z; a.w += gv * w.w;
        }
        pg2[br][kq][chunk] = a;
    }
    __syncthreads();
    if (t < 2 * OUT2) {
        const int br = t / OUT2, k = t % OUT2, kq = k / 4, comp = k % 4;
        float s = (br ? b2p : b2u)[k];
        #pragma unroll
        for (int ch = 0; ch < 5; ++ch)
            s += reinterpret_cast<const float*>(&pg2[br][kq][ch])[comp];
        g2s[br][k] = s;
    }
    __syncthreads();

    // --- softmax per branch: wave 0 -> br 0, wave 1 -> br 1 -----------------
    const int wave = t >> 6;
    const int lane = t & 63;
    if (wave < 2) {
        const int br = wave;
        float mx = -INFINITY;
        for (int k = lane; k < OUT2; k += 64) mx = fmaxf(mx, g2s[br][k]);
        #pragma unroll
        for (int off = 32; off > 0; off >>= 1) mx = fmaxf(mx, __shfl_xor(mx, off));
        float sum = 0.f;
        for (int k = lane; k < OUT2; k += 64) {
            const float e = expf(g2s[br][k] - mx);
            sm[br][k] = e;
            sum += e;
        }
        #pragma unroll
        for (int off = 32; off > 0; off >>= 1) sum += __shfl_xor(sum, off);
        const float inv = 1.0f / sum;
        for (int k = lane; k < OUT2; k += 64) sm[br][k] *= inv;
    }
    __syncthreads();

    // --- out = sigmoid((sm_u + sm_p) @ W_out + b_out) -----------------------
    if (wave == 0) {
        float s = 0.f;
        for (int k = lane; k < OUT2; k += 64)
            s += (sm[0][k] + sm[1][k]) * Wout[k];
        #pragma unroll
        for (int off = 32; off > 0; off >>= 1) s += __shfl_xor(s, off);
        if (lane == 0)
            out[0] = 1.0f / (1.0f + expf(-(s + bout[0])));
    }
}

// ---------------------------------------------------------------------------
extern "C" void kernel_launch(void* const* d_in, const int* in_sizes, int n_in,
                              void* d_out, int out_size, void* d_ws, size_t ws_size,
                              hipStream_t stream) {
    const float* userH = (const float*)d_in[0];
    const float* postH = (const float*)d_in[1];
    const float* W1u   = (const float*)d_in[2];
    const float* b1u   = (const float*)d_in[3];
    const float* W2u   = (const float*)d_in[4];
    const float* b2u   = (const float*)d_in[5];
    const float* W1p   = (const float*)d_in[6];
    const float* b1p   = (const float*)d_in[7];
    const float* W2p   = (const float*)d_in[8];
    const float* b2p   = (const float*)d_in[9];
    const float* Wout  = (const float*)d_in[10];
    const float* bout  = (const float*)d_in[11];

    float* partial = (float*)d_ws;   // 2*1024*200*4 = 1,638,400 bytes

    dim3 grid1(S1B, 2);
    colsum_kernel<<<grid1, 256, 0, stream>>>(userH, postH, partial);

    mlp_kernel<<<1, 1024, 0, stream>>>(partial,
                                       W1u, b1u, W2u, b2u,
                                       W1p, b1p, W2p, b2p,
                                       Wout, bout, (float*)d_out);
}